// Round 1
// baseline (24436.664 us; speedup 1.0000x reference)
//
#include <hip/hip_runtime.h>
#include <hip/hip_bf16.h>

#define B 2
#define T 2048
#define MEL 100
#define D 1024
#define H 16
#define L 6
#define DH 64
#define WIN 512
#define FF 4096
#define CD 1024
#define EPS 1e-5f

// ---------------------------------------------------------------------------
// time-embedding base: temb0[b,i] = i<512 ? sin(t_b*f_i) : cos(t_b*f_{i-512})
__global__ void temb0_kernel(const float* __restrict__ t, float* __restrict__ out) {
    int id = blockIdx.x * blockDim.x + threadIdx.x;
    if (id >= B * CD) return;
    int b = id / CD, i = id % CD;
    const int half = CD / 2;
    int j = (i < half) ? i : i - half;
    float f = expf(-logf(10000.f) * (float)j / (float)half);
    float ang = t[b] * f;
    out[id] = (i < half) ? sinf(ang) : cosf(ang);
}

// ---------------------------------------------------------------------------
// small row-matmul: out[r,n] = act(bias[n] + sum_k in[r,k]*W[k,n]); act: 0=none,1=silu
__global__ void smallmm_kernel(const float* __restrict__ in, const float* __restrict__ W,
                               const float* __restrict__ bias, float* __restrict__ out,
                               int rows, int K, int N, int act) {
    int id = blockIdx.x * blockDim.x + threadIdx.x;
    if (id >= rows * N) return;
    int n = id % N, r = id / N;
    float acc = bias[n];
    const float* ip = in + (size_t)r * K;
    for (int k = 0; k < K; ++k) acc += ip[k] * W[(size_t)k * N + n];
    if (act == 1) acc = acc / (1.f + expf(-acc));
    out[id] = acc;
}

// ---------------------------------------------------------------------------
// h = x @ W_in + b_in  (K=MEL=100)
__global__ __launch_bounds__(256) void in_proj_kernel(const float* __restrict__ x,
                                                      const float* __restrict__ W,
                                                      const float* __restrict__ bias,
                                                      float* __restrict__ h) {
    __shared__ float xs[MEL];
    int row = blockIdx.x;
    int tid = threadIdx.x;
    if (tid < MEL) xs[tid] = x[(size_t)row * MEL + tid];
    __syncthreads();
    for (int c = tid; c < D; c += 256) {
        float acc = bias[c];
        for (int k = 0; k < MEL; ++k) acc += xs[k] * W[(size_t)k * D + c];
        h[(size_t)row * D + c] = acc;
    }
}

// ---------------------------------------------------------------------------
// LayerNorm (+ optional ada scale/shift): out = ln(x)*(1+scale)+shift
__global__ __launch_bounds__(256) void ln_kernel(const float* __restrict__ x,
                                                 const float* __restrict__ ss,
                                                 float* __restrict__ out, int use_mod) {
    int row = blockIdx.x;           // b*T + t
    int b = row / T;
    int tid = threadIdx.x;
    float4 v = ((const float4*)(x + (size_t)row * D))[tid];
    float sum = v.x + v.y + v.z + v.w;
    float sq  = v.x * v.x + v.y * v.y + v.z * v.z + v.w * v.w;
    for (int off = 32; off; off >>= 1) {
        sum += __shfl_xor(sum, off);
        sq  += __shfl_xor(sq,  off);
    }
    __shared__ float smem[8];
    int wave = tid >> 6;
    if ((tid & 63) == 0) { smem[wave * 2] = sum; smem[wave * 2 + 1] = sq; }
    __syncthreads();
    sum = smem[0] + smem[2] + smem[4] + smem[6];
    sq  = smem[1] + smem[3] + smem[5] + smem[7];
    float mean = sum * (1.f / D);
    float var  = sq * (1.f / D) - mean * mean;
    float rstd = rsqrtf(var + EPS);
    int c = tid * 4;
    float4 o4;
    if (use_mod) {
        const float* sc = ss + (size_t)b * 2 * D;
        float4 s4  = *(const float4*)(sc + c);
        float4 sh4 = *(const float4*)(sc + D + c);
        o4.x = (v.x - mean) * rstd * (1.f + s4.x) + sh4.x;
        o4.y = (v.y - mean) * rstd * (1.f + s4.y) + sh4.y;
        o4.z = (v.z - mean) * rstd * (1.f + s4.z) + sh4.z;
        o4.w = (v.w - mean) * rstd * (1.f + s4.w) + sh4.w;
    } else {
        o4.x = (v.x - mean) * rstd;
        o4.y = (v.y - mean) * rstd;
        o4.z = (v.z - mean) * rstd;
        o4.w = (v.w - mean) * rstd;
    }
    ((float4*)(out + (size_t)row * D))[tid] = o4;
}

// ---------------------------------------------------------------------------
// fp32 GEMM: C[M,N] = A[M,K] @ W[K,N] + bias (+resid) (act: 0=none,1=gelu)
// tiles: 128x128x16, 256 threads, 8x8 micro-tile. M%128==0, N%128==0, K%16==0.
__global__ __launch_bounds__(256) void gemm_kernel(const float* __restrict__ A,
                                                   const float* __restrict__ W,
                                                   const float* __restrict__ bias,
                                                   const float* __restrict__ resid,
                                                   float* __restrict__ C,
                                                   int M, int N, int K, int act) {
    __shared__ float As[16][128];
    __shared__ float Bs[16][128];
    int bm = blockIdx.y * 128, bn = blockIdx.x * 128;
    int tid = threadIdx.x;
    int tx = tid & 15, ty = tid >> 4;
    float acc[8][8];
#pragma unroll
    for (int i = 0; i < 8; ++i)
#pragma unroll
        for (int j = 0; j < 8; ++j) acc[i][j] = 0.f;

    for (int k0 = 0; k0 < K; k0 += 16) {
        for (int f = tid; f < 512; f += 256) {          // A tile 128x16
            int row = f >> 2, c4 = (f & 3) << 2;
            float4 v = *(const float4*)(A + (size_t)(bm + row) * K + k0 + c4);
            As[c4 + 0][row] = v.x;
            As[c4 + 1][row] = v.y;
            As[c4 + 2][row] = v.z;
            As[c4 + 3][row] = v.w;
        }
        for (int f = tid; f < 512; f += 256) {          // B tile 16x128
            int row = f >> 5, col = (f & 31) << 2;
            *(float4*)&Bs[row][col] = *(const float4*)(W + (size_t)(k0 + row) * N + bn + col);
        }
        __syncthreads();
#pragma unroll
        for (int kk = 0; kk < 16; ++kk) {
            float4 a0 = *(const float4*)&As[kk][ty * 8];
            float4 a1 = *(const float4*)&As[kk][ty * 8 + 4];
            float4 b0 = *(const float4*)&Bs[kk][tx * 8];
            float4 b1 = *(const float4*)&Bs[kk][tx * 8 + 4];
            float a[8] = {a0.x, a0.y, a0.z, a0.w, a1.x, a1.y, a1.z, a1.w};
            float bb[8] = {b0.x, b0.y, b0.z, b0.w, b1.x, b1.y, b1.z, b1.w};
#pragma unroll
            for (int i = 0; i < 8; ++i)
#pragma unroll
                for (int j = 0; j < 8; ++j) acc[i][j] += a[i] * bb[j];
        }
        __syncthreads();
    }
#pragma unroll
    for (int i = 0; i < 8; ++i) {
        int m = bm + ty * 8 + i;
#pragma unroll
        for (int j = 0; j < 8; ++j) {
            int n = bn + tx * 8 + j;
            float v = acc[i][j] + bias[n];
            if (act == 1) v = 0.5f * v * (1.f + erff(v * 0.70710678118f));
            if (resid) v += resid[(size_t)m * N + n];
            C[(size_t)m * N + n] = v;
        }
    }
}

// ---------------------------------------------------------------------------
// RoPE applied in place to q and k inside qkv buffer [B,T,3,H,DH]
__global__ void rope_kernel(float* __restrict__ qkv) {
    int id = blockIdx.x * blockDim.x + threadIdx.x;   // B*T*H*(DH/2) = 2^21
    if (id >= B * T * H * (DH / 2)) return;
    int i  = id & 31;
    int hh = (id >> 5) & 15;
    int t  = (id >> 9) & 2047;
    int b  = id >> 20;
    float freq = expf(-logf(10000.f) * (float)(2 * i) / (float)DH);
    float ang = (float)t * freq;
    float s, c;
    sincosf(ang, &s, &c);
    size_t base = ((size_t)(b * T + t) * 3) * D + hh * DH;
    float q0 = qkv[base + 2 * i], q1 = qkv[base + 2 * i + 1];
    qkv[base + 2 * i]     = q0 * c - q1 * s;
    qkv[base + 2 * i + 1] = q0 * s + q1 * c;
    size_t kb = base + D;
    float k0 = qkv[kb + 2 * i], k1 = qkv[kb + 2 * i + 1];
    qkv[kb + 2 * i]     = k0 * c - k1 * s;
    qkv[kb + 2 * i + 1] = k0 * s + k1 * c;
}

// ---------------------------------------------------------------------------
// windowed attention: all queries attend to the last WIN keys with mask j<=q.
// one wave per (b, head, q).
__global__ __launch_bounds__(64) void attn_kernel(const float* __restrict__ qkv,
                                                  float* __restrict__ o) {
    __shared__ float qs[DH];
    __shared__ float ps[WIN];
    int lane = threadIdx.x;
    int idx = blockIdx.x;
    int q  = idx & (T - 1);
    int hd = (idx >> 11) & (H - 1);
    int b  = idx >> 15;

    qs[lane] = qkv[((size_t)(b * T + q) * 3 + 0) * D + hd * DH + lane];
    __syncthreads();

    int jmax = q < (WIN - 1) ? q : (WIN - 1);
    float s[8];
    float mloc = -INFINITY;
#pragma unroll
    for (int i = 0; i < 8; ++i) {
        int j = lane + 64 * i;
        if (j <= jmax) {
            const float* kp = qkv + ((size_t)(b * T + (T - WIN) + j) * 3 + 1) * D + hd * DH;
            float acc = 0.f;
#pragma unroll
            for (int d4 = 0; d4 < DH; d4 += 4) {
                float4 kv = *(const float4*)(kp + d4);
                float4 qv = *(const float4*)(qs + d4);
                acc += qv.x * kv.x + qv.y * kv.y + qv.z * kv.z + qv.w * kv.w;
            }
            acc *= 0.125f;   // 1/sqrt(DH)
            s[i] = acc;
            mloc = fmaxf(mloc, acc);
        } else {
            s[i] = -INFINITY;
        }
    }
    for (int off = 32; off; off >>= 1) mloc = fmaxf(mloc, __shfl_xor(mloc, off));
    float lsum = 0.f;
    float p[8];
#pragma unroll
    for (int i = 0; i < 8; ++i) {
        int j = lane + 64 * i;
        float pv = (j <= jmax) ? expf(s[i] - mloc) : 0.f;
        p[i] = pv;
        lsum += pv;
    }
    for (int off = 32; off; off >>= 1) lsum += __shfl_xor(lsum, off);
    float inv = 1.f / lsum;
#pragma unroll
    for (int i = 0; i < 8; ++i) ps[lane + 64 * i] = p[i] * inv;
    __syncthreads();

    // phase 2: lane = output dim d
    float acc = 0.f;
    const float* vbase = qkv + ((size_t)(b * T + (T - WIN)) * 3 + 2) * D + hd * DH + lane;
    for (int j = 0; j <= jmax; ++j) acc += ps[j] * vbase[(size_t)j * 3 * D];
    o[(size_t)(b * T + q) * D + hd * DH + lane] = acc;
}

// ---------------------------------------------------------------------------
// out = hn @ W_out + b_out  (N=MEL=100)
__global__ __launch_bounds__(128) void out_proj_kernel(const float* __restrict__ hn,
                                                       const float* __restrict__ W,
                                                       const float* __restrict__ bias,
                                                       float* __restrict__ out) {
    __shared__ float hs[D];
    int row = blockIdx.x;
    int tid = threadIdx.x;
    for (int c = tid; c < D; c += 128) hs[c] = hn[(size_t)row * D + c];
    __syncthreads();
    if (tid < MEL) {
        float acc = bias[tid];
        for (int k = 0; k < D; ++k) acc += hs[k] * W[(size_t)k * MEL + tid];
        out[(size_t)row * MEL + tid] = acc;
    }
}

// ---------------------------------------------------------------------------
extern "C" void kernel_launch(void* const* d_in, const int* in_sizes, int n_in,
                              void* d_out, int out_size, void* d_ws, size_t ws_size,
                              hipStream_t stream) {
    const float* x      = (const float*)d_in[0];
    const float* t      = (const float*)d_in[1];
    const float* W_in   = (const float*)d_in[2];
    const float* b_in   = (const float*)d_in[3];
    const float* Wt1    = (const float*)d_in[4];
    const float* bt1    = (const float*)d_in[5];
    const float* Wt2    = (const float*)d_in[6];
    const float* bt2    = (const float*)d_in[7];
    const float* Wcm    = (const float*)d_in[8];
    const float* bcm    = (const float*)d_in[9];
    const float* ada1_W = (const float*)d_in[10];
    const float* ada1_b = (const float*)d_in[11];
    const float* qkv_W  = (const float*)d_in[12];
    const float* qkv_b  = (const float*)d_in[13];
    const float* attno_W= (const float*)d_in[14];
    const float* attno_b= (const float*)d_in[15];
    const float* ada2_W = (const float*)d_in[16];
    const float* ada2_b = (const float*)d_in[17];
    const float* mlp_W1 = (const float*)d_in[18];
    const float* mlp_b1 = (const float*)d_in[19];
    const float* mlp_W2 = (const float*)d_in[20];
    const float* mlp_b2 = (const float*)d_in[21];
    const float* W_out  = (const float*)d_in[22];
    const float* b_out  = (const float*)d_in[23];
    float* out = (float*)d_out;

    float* ws    = (float*)d_ws;
    float* h     = ws;                              // B*T*D   = 4,194,304
    float* hn    = ws + 4194304;                    // B*T*D
    float* big   = ws + 8388608;                    // B*T*FF  = 16,777,216 (qkv | ff)
    float* obuf  = big + 12582912;                  // B*T*D tail of big (qkv uses 12.58M)
    float* temb0 = ws + 25165824;                   // B*CD
    float* tembh = temb0 + B * CD;
    float* temb2 = tembh + B * CD;
    float* cond  = temb2 + B * CD;                  // cond_act, B*D
    float* ss1   = cond + B * D;                    // L*B*2D = 24576
    float* ss2   = ss1 + L * B * 2 * D;

    const int M = B * T;                            // 4096

    // time-embedding chain
    temb0_kernel<<<(B * CD + 255) / 256, 256, 0, stream>>>(t, temb0);
    smallmm_kernel<<<(B * CD + 255) / 256, 256, 0, stream>>>(temb0, Wt1, bt1, tembh, B, CD, CD, 1);
    smallmm_kernel<<<(B * CD + 255) / 256, 256, 0, stream>>>(tembh, Wt2, bt2, temb2, B, CD, CD, 0);
    smallmm_kernel<<<(B * D + 255) / 256, 256, 0, stream>>>(temb2, Wcm, bcm, cond, B, CD, D, 1);
    // ada scale/shift for all layers
    for (int l = 0; l < L; ++l) {
        smallmm_kernel<<<(B * 2 * D + 255) / 256, 256, 0, stream>>>(
            cond, ada1_W + (size_t)l * D * 2 * D, ada1_b + (size_t)l * 2 * D,
            ss1 + (size_t)l * B * 2 * D, B, D, 2 * D, 0);
        smallmm_kernel<<<(B * 2 * D + 255) / 256, 256, 0, stream>>>(
            cond, ada2_W + (size_t)l * D * 2 * D, ada2_b + (size_t)l * 2 * D,
            ss2 + (size_t)l * B * 2 * D, B, D, 2 * D, 0);
    }

    in_proj_kernel<<<M, 256, 0, stream>>>(x, W_in, b_in, h);

    for (int l = 0; l < L; ++l) {
        ln_kernel<<<M, 256, 0, stream>>>(h, ss1 + (size_t)l * B * 2 * D, hn, 1);
        gemm_kernel<<<dim3(3 * D / 128, M / 128), 256, 0, stream>>>(
            hn, qkv_W + (size_t)l * D * 3 * D, qkv_b + (size_t)l * 3 * D,
            nullptr, big, M, 3 * D, D, 0);
        rope_kernel<<<(B * T * H * (DH / 2) + 255) / 256, 256, 0, stream>>>(big);
        attn_kernel<<<B * H * T, 64, 0, stream>>>(big, obuf);
        gemm_kernel<<<dim3(D / 128, M / 128), 256, 0, stream>>>(
            obuf, attno_W + (size_t)l * D * D, attno_b + (size_t)l * D,
            h, h, M, D, D, 0);
        ln_kernel<<<M, 256, 0, stream>>>(h, ss2 + (size_t)l * B * 2 * D, hn, 1);
        gemm_kernel<<<dim3(FF / 128, M / 128), 256, 0, stream>>>(
            hn, mlp_W1 + (size_t)l * D * FF, mlp_b1 + (size_t)l * FF,
            nullptr, big, M, FF, D, 1);
        gemm_kernel<<<dim3(D / 128, M / 128), 256, 0, stream>>>(
            big, mlp_W2 + (size_t)l * FF * D, mlp_b2 + (size_t)l * D,
            h, h, M, D, FF, 0);
    }

    ln_kernel<<<M, 256, 0, stream>>>(h, nullptr, hn, 0);
    out_proj_kernel<<<M, 128, 0, stream>>>(hn, W_out, b_out, out);
}

// Round 2
// 15360.522 us; speedup vs baseline: 1.5909x; 1.5909x over previous
//
#include <hip/hip_runtime.h>
#include <hip/hip_bf16.h>

#define B 2
#define T 2048
#define MEL 100
#define D 1024
#define H 16
#define L 6
#define DH 64
#define WIN 512
#define FF 4096
#define CD 1024
#define EPS 1e-5f

typedef __attribute__((ext_vector_type(8))) short bshort8;   // 8 bf16 = 4 VGPRs
typedef __attribute__((ext_vector_type(4))) float f32x4;

// ---------------------------------------------------------------------------
__device__ __forceinline__ void gload16(const void* g, void* l) {
    __builtin_amdgcn_global_load_lds(
        (const __attribute__((address_space(1))) unsigned int*)g,
        (__attribute__((address_space(3))) unsigned int*)l, 16, 0, 0);
}

// ---------------------------------------------------------------------------
// time-embedding base: temb0[b,i] = i<512 ? sin(t_b*f_i) : cos(t_b*f_{i-512})
__global__ void temb0_kernel(const float* __restrict__ t, float* __restrict__ out) {
    int id = blockIdx.x * blockDim.x + threadIdx.x;
    if (id >= B * CD) return;
    int b = id / CD, i = id % CD;
    const int half = CD / 2;
    int j = (i < half) ? i : i - half;
    float f = expf(-logf(10000.f) * (float)j / (float)half);
    float ang = t[b] * f;
    out[id] = (i < half) ? sinf(ang) : cosf(ang);
}

// ---------------------------------------------------------------------------
// small row-matmul: out[r,n] = act(bias[n] + sum_k in[r,k]*W[k,n]); act: 0=none,1=silu
__global__ void smallmm_kernel(const float* __restrict__ in, const float* __restrict__ W,
                               const float* __restrict__ bias, float* __restrict__ out,
                               int rows, int K, int N, int act) {
    int id = blockIdx.x * blockDim.x + threadIdx.x;
    if (id >= rows * N) return;
    int n = id % N, r = id / N;
    float acc = bias[n];
    const float* ip = in + (size_t)r * K;
    for (int k = 0; k < K; ++k) acc += ip[k] * W[(size_t)k * N + n];
    if (act == 1) acc = acc / (1.f + expf(-acc));
    out[id] = acc;
}

// ---------------------------------------------------------------------------
// h = x @ W_in + b_in  (K=MEL=100)
__global__ __launch_bounds__(256) void in_proj_kernel(const float* __restrict__ x,
                                                      const float* __restrict__ W,
                                                      const float* __restrict__ bias,
                                                      float* __restrict__ h) {
    __shared__ float xs[MEL];
    int row = blockIdx.x;
    int tid = threadIdx.x;
    if (tid < MEL) xs[tid] = x[(size_t)row * MEL + tid];
    __syncthreads();
    for (int c = tid; c < D; c += 256) {
        float acc = bias[c];
        for (int k = 0; k < MEL; ++k) acc += xs[k] * W[(size_t)k * D + c];
        h[(size_t)row * D + c] = acc;
    }
}

// ---------------------------------------------------------------------------
// LayerNorm (+ optional ada scale/shift). out_bf=1 -> bf16 output, else fp32.
__global__ __launch_bounds__(256) void ln_kernel(const float* __restrict__ x,
                                                 const float* __restrict__ ss,
                                                 void* __restrict__ out,
                                                 int use_mod, int out_bf) {
    int row = blockIdx.x;           // b*T + t
    int b = row / T;
    int tid = threadIdx.x;
    float4 v = ((const float4*)(x + (size_t)row * D))[tid];
    float sum = v.x + v.y + v.z + v.w;
    float sq  = v.x * v.x + v.y * v.y + v.z * v.z + v.w * v.w;
    for (int off = 32; off; off >>= 1) {
        sum += __shfl_xor(sum, off);
        sq  += __shfl_xor(sq,  off);
    }
    __shared__ float smem[8];
    int wave = tid >> 6;
    if ((tid & 63) == 0) { smem[wave * 2] = sum; smem[wave * 2 + 1] = sq; }
    __syncthreads();
    sum = smem[0] + smem[2] + smem[4] + smem[6];
    sq  = smem[1] + smem[3] + smem[5] + smem[7];
    float mean = sum * (1.f / D);
    float var  = sq * (1.f / D) - mean * mean;
    float rstd = rsqrtf(var + EPS);
    int c = tid * 4;
    float4 o4;
    if (use_mod) {
        const float* sc = ss + (size_t)b * 2 * D;
        float4 s4  = *(const float4*)(sc + c);
        float4 sh4 = *(const float4*)(sc + D + c);
        o4.x = (v.x - mean) * rstd * (1.f + s4.x) + sh4.x;
        o4.y = (v.y - mean) * rstd * (1.f + s4.y) + sh4.y;
        o4.z = (v.z - mean) * rstd * (1.f + s4.z) + sh4.z;
        o4.w = (v.w - mean) * rstd * (1.f + s4.w) + sh4.w;
    } else {
        o4.x = (v.x - mean) * rstd;
        o4.y = (v.y - mean) * rstd;
        o4.z = (v.z - mean) * rstd;
        o4.w = (v.w - mean) * rstd;
    }
    if (out_bf) {
        __hip_bfloat16* op = (__hip_bfloat16*)out + (size_t)row * D + c;
        op[0] = __float2bfloat16(o4.x);
        op[1] = __float2bfloat16(o4.y);
        op[2] = __float2bfloat16(o4.z);
        op[3] = __float2bfloat16(o4.w);
    } else {
        ((float4*)((float*)out + (size_t)row * D))[tid] = o4;
    }
}

// ---------------------------------------------------------------------------
// fp32 [K,N] -> bf16 [N,K] transpose (weights). block (32,8), 32x32 tiles.
__global__ __launch_bounds__(256) void transpose_bf16_kernel(const float* __restrict__ W,
                                                             __hip_bfloat16* __restrict__ Wt,
                                                             int K, int N) {
    __shared__ float tile[32][33];
    int nt = blockIdx.x * 32, kt = blockIdx.y * 32;
    int tx = threadIdx.x, ty = threadIdx.y;
#pragma unroll
    for (int i = 0; i < 32; i += 8)
        tile[ty + i][tx] = W[(size_t)(kt + ty + i) * N + nt + tx];
    __syncthreads();
#pragma unroll
    for (int i = 0; i < 32; i += 8)
        Wt[(size_t)(nt + ty + i) * K + kt + tx] = __float2bfloat16(tile[tx][ty + i]);
}

// ---------------------------------------------------------------------------
// bf16 MFMA GEMM: C[M,N] = A[M,K](bf16) @ Bt[N,K](bf16)^T + bias (+resid)
// act: 0=none, 1=exact gelu. out_bf: write bf16 else fp32.
// Tiles: BM=BN=128, BK=64. 256 threads = 4 waves, each wave 64x64 (4x4 MFMA tiles).
// LDS: padded row stride 72 elements (9 groups of 8) -> global_load_lds friendly
// and 2-way-only bank aliasing on ds_read_b128.
#define BK 64
#define LDK 72
__global__ __launch_bounds__(256) void gemm_bf16_kernel(const __hip_bfloat16* __restrict__ A,
                                                        const __hip_bfloat16* __restrict__ Bt,
                                                        const float* __restrict__ bias,
                                                        const float* __restrict__ resid,
                                                        void* __restrict__ Cout,
                                                        int M, int N, int K,
                                                        int act, int out_bf) {
    __shared__ short LA[128 * LDK];   // 18 KB
    __shared__ short LB[128 * LDK];   // 18 KB
    const int tid = threadIdx.x;
    const int wave = tid >> 6, lane = tid & 63;
    const int bm = blockIdx.y * 128, bn = blockIdx.x * 128;
    const int wm = (wave >> 1) * 64, wn = (wave & 1) * 64;
    const int l15 = lane & 15, l4 = lane >> 4;

    f32x4 acc[4][4];
#pragma unroll
    for (int i = 0; i < 4; ++i)
#pragma unroll
        for (int j = 0; j < 4; ++j) acc[i][j] = (f32x4){0.f, 0.f, 0.f, 0.f};

    for (int k0 = 0; k0 < K; k0 += BK) {
        // stage A tile [128][64] and Bt tile [128][64] into padded LDS.
        // 18 wave-issues per tile; issue t covers flattened groups t*64..t*64+63.
        for (int t = wave; t < 18; t += 4) {
            int Gi = t * 64 + lane;
            int row = Gi / 9, g = Gi % 9;
            int gc = (g < 8) ? g * 8 : 0;              // pad group -> dummy load
            gload16(A + (size_t)(bm + row) * K + k0 + gc, (void*)&LA[t * 512]);
        }
        for (int t = wave; t < 18; t += 4) {
            int Gi = t * 64 + lane;
            int row = Gi / 9, g = Gi % 9;
            int gc = (g < 8) ? g * 8 : 0;
            gload16(Bt + (size_t)(bn + row) * K + k0 + gc, (void*)&LB[t * 512]);
        }
        __syncthreads();   // compiler emits vmcnt(0) drain before barrier
#pragma unroll
        for (int ks = 0; ks < 2; ++ks) {
            const int kb = ks * 32 + l4 * 8;
            bshort8 a[4], b[4];
#pragma unroll
            for (int i = 0; i < 4; ++i)
                a[i] = *(const bshort8*)&LA[(wm + i * 16 + l15) * LDK + kb];
#pragma unroll
            for (int i = 0; i < 4; ++i)
                b[i] = *(const bshort8*)&LB[(wn + i * 16 + l15) * LDK + kb];
#pragma unroll
            for (int i = 0; i < 4; ++i)
#pragma unroll
                for (int j = 0; j < 4; ++j)
                    acc[i][j] = __builtin_amdgcn_mfma_f32_16x16x32_bf16(a[i], b[j], acc[i][j], 0, 0, 0);
        }
        __syncthreads();
    }

    // epilogue: C/D layout col=lane&15, row=(lane>>4)*4+reg  [m89-verified]
#pragma unroll
    for (int im = 0; im < 4; ++im) {
#pragma unroll
        for (int in = 0; in < 4; ++in) {
            int col = bn + wn + in * 16 + l15;
            int row0 = bm + wm + im * 16 + l4 * 4;
            float bi = bias[col];
#pragma unroll
            for (int r = 0; r < 4; ++r) {
                float v = acc[im][in][r] + bi;
                if (act == 1) v = 0.5f * v * (1.f + erff(v * 0.70710678118f));
                size_t idx = (size_t)(row0 + r) * N + col;
                if (resid) v += resid[idx];
                if (out_bf) ((__hip_bfloat16*)Cout)[idx] = __float2bfloat16(v);
                else        ((float*)Cout)[idx] = v;
            }
        }
    }
}

// ---------------------------------------------------------------------------
// rope tables in double precision: cs[t][0:32]=cos, cs[t][32:64]=sin
__global__ void rope_tables_kernel(float* __restrict__ cs) {
    int id = blockIdx.x * blockDim.x + threadIdx.x;   // T*32
    if (id >= T * 32) return;
    int t = id >> 5, i = id & 31;
    double freq = 1.0 / pow(10000.0, (double)(2 * i) / (double)DH);
    double ang = (double)t * freq;
    cs[t * 64 + i]      = (float)cos(ang);
    cs[t * 64 + 32 + i] = (float)sin(ang);
}

// ---------------------------------------------------------------------------
// RoPE applied in place to q and k inside qkv buffer [B,T,3,H,DH]
__global__ void rope_kernel(float* __restrict__ qkv, const float* __restrict__ cs) {
    int id = blockIdx.x * blockDim.x + threadIdx.x;   // B*T*H*(DH/2) = 2^21
    if (id >= B * T * H * (DH / 2)) return;
    int i  = id & 31;
    int hh = (id >> 5) & 15;
    int t  = (id >> 9) & 2047;
    int b  = id >> 20;
    float c = cs[t * 64 + i];
    float s = cs[t * 64 + 32 + i];
    size_t base = ((size_t)(b * T + t) * 3) * D + hh * DH;
    float q0 = qkv[base + 2 * i], q1 = qkv[base + 2 * i + 1];
    qkv[base + 2 * i]     = q0 * c - q1 * s;
    qkv[base + 2 * i + 1] = q0 * s + q1 * c;
    size_t kb = base + D;
    float k0 = qkv[kb + 2 * i], k1 = qkv[kb + 2 * i + 1];
    qkv[kb + 2 * i]     = k0 * c - k1 * s;
    qkv[kb + 2 * i + 1] = k0 * s + k1 * c;
}

// ---------------------------------------------------------------------------
// windowed attention (fp32 math), bf16 output. one wave per (b, head, q).
__global__ __launch_bounds__(64) void attn_kernel(const float* __restrict__ qkv,
                                                  __hip_bfloat16* __restrict__ o) {
    __shared__ float qs[DH];
    __shared__ float ps[WIN];
    int lane = threadIdx.x;
    int idx = blockIdx.x;
    int q  = idx & (T - 1);
    int hd = (idx >> 11) & (H - 1);
    int b  = idx >> 15;

    qs[lane] = qkv[((size_t)(b * T + q) * 3 + 0) * D + hd * DH + lane];
    __syncthreads();

    int jmax = q < (WIN - 1) ? q : (WIN - 1);
    float s[8];
    float mloc = -INFINITY;
#pragma unroll
    for (int i = 0; i < 8; ++i) {
        int j = lane + 64 * i;
        if (j <= jmax) {
            const float* kp = qkv + ((size_t)(b * T + (T - WIN) + j) * 3 + 1) * D + hd * DH;
            float acc = 0.f;
#pragma unroll
            for (int d4 = 0; d4 < DH; d4 += 4) {
                float4 kv = *(const float4*)(kp + d4);
                float4 qv = *(const float4*)(qs + d4);
                acc += qv.x * kv.x + qv.y * kv.y + qv.z * kv.z + qv.w * kv.w;
            }
            acc *= 0.125f;
            s[i] = acc;
            mloc = fmaxf(mloc, acc);
        } else {
            s[i] = -INFINITY;
        }
    }
    for (int off = 32; off; off >>= 1) mloc = fmaxf(mloc, __shfl_xor(mloc, off));
    float lsum = 0.f;
    float p[8];
#pragma unroll
    for (int i = 0; i < 8; ++i) {
        int j = lane + 64 * i;
        float pv = (j <= jmax) ? expf(s[i] - mloc) : 0.f;
        p[i] = pv;
        lsum += pv;
    }
    for (int off = 32; off; off >>= 1) lsum += __shfl_xor(lsum, off);
    float inv = 1.f / lsum;
#pragma unroll
    for (int i = 0; i < 8; ++i) ps[lane + 64 * i] = p[i] * inv;
    __syncthreads();

    float acc = 0.f;
    const float* vbase = qkv + ((size_t)(b * T + (T - WIN)) * 3 + 2) * D + hd * DH + lane;
    for (int j = 0; j <= jmax; ++j) acc += ps[j] * vbase[(size_t)j * 3 * D];
    o[(size_t)(b * T + q) * D + hd * DH + lane] = __float2bfloat16(acc);
}

// ---------------------------------------------------------------------------
// out = hn @ W_out + b_out  (N=MEL=100)
__global__ __launch_bounds__(128) void out_proj_kernel(const float* __restrict__ hn,
                                                       const float* __restrict__ W,
                                                       const float* __restrict__ bias,
                                                       float* __restrict__ out) {
    __shared__ float hs[D];
    int row = blockIdx.x;
    int tid = threadIdx.x;
    for (int c = tid; c < D; c += 128) hs[c] = hn[(size_t)row * D + c];
    __syncthreads();
    if (tid < MEL) {
        float acc = bias[tid];
        for (int k = 0; k < D; ++k) acc += hs[k] * W[(size_t)k * MEL + tid];
        out[(size_t)row * MEL + tid] = acc;
    }
}

// ---------------------------------------------------------------------------
extern "C" void kernel_launch(void* const* d_in, const int* in_sizes, int n_in,
                              void* d_out, int out_size, void* d_ws, size_t ws_size,
                              hipStream_t stream) {
    const float* x      = (const float*)d_in[0];
    const float* t      = (const float*)d_in[1];
    const float* W_in   = (const float*)d_in[2];
    const float* b_in   = (const float*)d_in[3];
    const float* Wt1    = (const float*)d_in[4];
    const float* bt1    = (const float*)d_in[5];
    const float* Wt2    = (const float*)d_in[6];
    const float* bt2    = (const float*)d_in[7];
    const float* Wcm    = (const float*)d_in[8];
    const float* bcm    = (const float*)d_in[9];
    const float* ada1_W = (const float*)d_in[10];
    const float* ada1_b = (const float*)d_in[11];
    const float* qkv_W  = (const float*)d_in[12];
    const float* qkv_b  = (const float*)d_in[13];
    const float* attno_W= (const float*)d_in[14];
    const float* attno_b= (const float*)d_in[15];
    const float* ada2_W = (const float*)d_in[16];
    const float* ada2_b = (const float*)d_in[17];
    const float* mlp_W1 = (const float*)d_in[18];
    const float* mlp_b1 = (const float*)d_in[19];
    const float* mlp_W2 = (const float*)d_in[20];
    const float* mlp_b2 = (const float*)d_in[21];
    const float* W_out  = (const float*)d_in[22];
    const float* b_out  = (const float*)d_in[23];
    float* out = (float*)d_out;

    float* ws = (float*)d_ws;
    // layout (fp32 elements):
    float* h      = ws;                                   //  4,194,304
    float* qkvreg = ws + 4194304;                         // 12,582,912 (qkv fp32 | ffbf bf16 | final hn fp32)
    __hip_bfloat16* ffbf = (__hip_bfloat16*)qkvreg;
    float* ropecs = ws + 16777216;                        //    131,072 (T*64)
    __hip_bfloat16* hnbf = (__hip_bfloat16*)(ws + 16908288);   // 4,194,304 bf16
    __hip_bfloat16* obf  = (__hip_bfloat16*)(ws + 19005440);   // 4,194,304 bf16
    __hip_bfloat16* wtb  = (__hip_bfloat16*)(ws + 21102592);   // 12,582,912 bf16 (per-layer Wt)
    __hip_bfloat16* wt_qkv = wtb;                   // 3,145,728
    __hip_bfloat16* wt_at  = wtb + 3145728;         // 1,048,576
    __hip_bfloat16* wt_m1  = wtb + 4194304;         // 4,194,304
    __hip_bfloat16* wt_m2  = wtb + 8388608;         // 4,194,304
    float* temb0 = ws + 27394048;                   // B*CD
    float* tembh = temb0 + B * CD;
    float* temb2 = tembh + B * CD;
    float* cond  = temb2 + B * CD;
    float* ss1   = cond + B * D;                    // L*B*2D
    float* ss2   = ss1 + L * B * 2 * D;

    const int M = B * T;   // 4096

    rope_tables_kernel<<<(T * 32 + 255) / 256, 256, 0, stream>>>(ropecs);

    // time-embedding chain
    temb0_kernel<<<(B * CD + 255) / 256, 256, 0, stream>>>(t, temb0);
    smallmm_kernel<<<(B * CD + 255) / 256, 256, 0, stream>>>(temb0, Wt1, bt1, tembh, B, CD, CD, 1);
    smallmm_kernel<<<(B * CD + 255) / 256, 256, 0, stream>>>(tembh, Wt2, bt2, temb2, B, CD, CD, 0);
    smallmm_kernel<<<(B * D + 255) / 256, 256, 0, stream>>>(temb2, Wcm, bcm, cond, B, CD, D, 1);
    for (int l = 0; l < L; ++l) {
        smallmm_kernel<<<(B * 2 * D + 255) / 256, 256, 0, stream>>>(
            cond, ada1_W + (size_t)l * D * 2 * D, ada1_b + (size_t)l * 2 * D,
            ss1 + (size_t)l * B * 2 * D, B, D, 2 * D, 0);
        smallmm_kernel<<<(B * 2 * D + 255) / 256, 256, 0, stream>>>(
            cond, ada2_W + (size_t)l * D * 2 * D, ada2_b + (size_t)l * 2 * D,
            ss2 + (size_t)l * B * 2 * D, B, D, 2 * D, 0);
    }

    in_proj_kernel<<<M, 256, 0, stream>>>(x, W_in, b_in, h);

    for (int l = 0; l < L; ++l) {
        // per-layer weight convert+transpose: W[K,N] fp32 -> Wt[N,K] bf16
        transpose_bf16_kernel<<<dim3(3 * D / 32, D / 32), dim3(32, 8), 0, stream>>>(
            qkv_W + (size_t)l * D * 3 * D, wt_qkv, D, 3 * D);
        transpose_bf16_kernel<<<dim3(D / 32, D / 32), dim3(32, 8), 0, stream>>>(
            attno_W + (size_t)l * D * D, wt_at, D, D);
        transpose_bf16_kernel<<<dim3(FF / 32, D / 32), dim3(32, 8), 0, stream>>>(
            mlp_W1 + (size_t)l * D * FF, wt_m1, D, FF);
        transpose_bf16_kernel<<<dim3(D / 32, FF / 32), dim3(32, 8), 0, stream>>>(
            mlp_W2 + (size_t)l * FF * D, wt_m2, FF, D);

        ln_kernel<<<M, 256, 0, stream>>>(h, ss1 + (size_t)l * B * 2 * D, hnbf, 1, 1);
        gemm_bf16_kernel<<<dim3(3 * D / 128, M / 128), 256, 0, stream>>>(
            hnbf, wt_qkv, qkv_b + (size_t)l * 3 * D, nullptr, qkvreg,
            M, 3 * D, D, 0, 0);
        rope_kernel<<<(B * T * H * (DH / 2) + 255) / 256, 256, 0, stream>>>(qkvreg, ropecs);
        attn_kernel<<<B * H * T, 64, 0, stream>>>(qkvreg, obf);
        gemm_bf16_kernel<<<dim3(D / 128, M / 128), 256, 0, stream>>>(
            obf, wt_at, attno_b + (size_t)l * D, h, h, M, D, D, 0, 0);
        ln_kernel<<<M, 256, 0, stream>>>(h, ss2 + (size_t)l * B * 2 * D, hnbf, 1, 1);
        gemm_bf16_kernel<<<dim3(FF / 128, M / 128), 256, 0, stream>>>(
            hnbf, wt_m1, mlp_b1 + (size_t)l * FF, nullptr, ffbf,
            M, FF, D, 1, 1);
        gemm_bf16_kernel<<<dim3(D / 128, M / 128), 256, 0, stream>>>(
            ffbf, wt_m2, mlp_b2 + (size_t)l * D, h, h, M, D, FF, 0, 0);
    }

    ln_kernel<<<M, 256, 0, stream>>>(h, nullptr, qkvreg, 0, 0);
    out_proj_kernel<<<M, 128, 0, stream>>>(qkvreg, W_out, b_out, out);
}

// Round 4
// 2998.054 us; speedup vs baseline: 8.1508x; 5.1235x over previous
//
#include <hip/hip_runtime.h>
#include <hip/hip_bf16.h>

#define B 2
#define T 2048
#define MEL 100
#define D 1024
#define H 16
#define L 6
#define DH 64
#define WIN 512
#define FF 4096
#define CD 1024
#define EPS 1e-5f

typedef __attribute__((ext_vector_type(8))) short bshort8;   // 8 bf16 = 4 VGPRs
typedef __attribute__((ext_vector_type(4))) float f32x4;

// ---------------------------------------------------------------------------
__device__ __forceinline__ void gload16(const void* g, void* l) {
    __builtin_amdgcn_global_load_lds(
        (const __attribute__((address_space(1))) unsigned int*)g,
        (__attribute__((address_space(3))) unsigned int*)l, 16, 0, 0);
}

__device__ __forceinline__ float bf2f(__hip_bfloat16 v) { return __bfloat162float(v); }

// ---------------------------------------------------------------------------
__global__ void temb0_kernel(const float* __restrict__ t, float* __restrict__ out) {
    int id = blockIdx.x * blockDim.x + threadIdx.x;
    if (id >= B * CD) return;
    int b = id / CD, i = id % CD;
    const int half = CD / 2;
    int j = (i < half) ? i : i - half;
    float f = expf(-logf(10000.f) * (float)j / (float)half);
    float ang = t[b] * f;
    out[id] = (i < half) ? sinf(ang) : cosf(ang);
}

// ---------------------------------------------------------------------------
// split-K GEMV partial: scratch[ks][idx] = sum over k-chunk of in[b,k]*W[k,n]
__global__ __launch_bounds__(256) void gemv_part_kernel(const float* __restrict__ in,
                                                        const float* __restrict__ W,
                                                        float* __restrict__ scratch,
                                                        int K, int N, int kchunk) {
    int idx = blockIdx.x * 256 + threadIdx.x;       // rows*N total (2048)
    int ks = blockIdx.y;
    int b = idx / N, n = idx % N;
    const float* ip = in + (size_t)b * K + ks * kchunk;
    const float* wp = W + (size_t)ks * kchunk * N + n;
    float acc = 0.f;
    for (int k = 0; k < kchunk; ++k) acc += ip[k] * wp[(size_t)k * N];
    scratch[(size_t)ks * (gridDim.x * 256) + idx] = acc;
}

__global__ void gemv_reduce_kernel(const float* __restrict__ scratch,
                                   const float* __restrict__ bias,
                                   float* __restrict__ out,
                                   int total, int N, int NS, int act) {
    int idx = blockIdx.x * 256 + threadIdx.x;
    if (idx >= total) return;
    float acc = bias[idx % N];
    for (int s = 0; s < NS; ++s) acc += scratch[(size_t)s * total + idx];
    if (act) acc = acc / (1.f + expf(-acc));
    out[idx] = acc;
}

// ---------------------------------------------------------------------------
// all 12 ada GEMVs in one launch. grid (16, 4, 12). B*2D = 4096 outputs per matrix.
__global__ __launch_bounds__(256) void ada_part_kernel(const float* __restrict__ cond,
                                                       const float* __restrict__ ada1_W,
                                                       const float* __restrict__ ada2_W,
                                                       float* __restrict__ scratch) {
    int z = blockIdx.z;
    int l = z >> 1, which = z & 1;
    const float* W = (which ? ada2_W : ada1_W) + (size_t)l * D * 2 * D;
    int idx = blockIdx.x * 256 + threadIdx.x;       // 0..4095 = b*2048 + n
    int b = idx >> 11, n = idx & 2047;
    const float* ip = cond + b * D + blockIdx.y * 256;
    const float* wp = W + (size_t)blockIdx.y * 256 * 2048 + n;
    float acc = 0.f;
    for (int k = 0; k < 256; ++k) acc += ip[k] * wp[(size_t)k * 2048];
    scratch[((size_t)(z * 4 + blockIdx.y)) * 4096 + idx] = acc;
}

__global__ void ada_reduce_kernel(const float* __restrict__ scratch,
                                  const float* __restrict__ ada1_b,
                                  const float* __restrict__ ada2_b,
                                  float* __restrict__ ss1, float* __restrict__ ss2) {
    int id = blockIdx.x * 256 + threadIdx.x;        // 12*4096
    if (id >= 12 * 4096) return;
    int z = id / 4096, rem = id % 4096;
    int l = z >> 1, which = z & 1;
    int n = rem & 2047;
    float acc = 0.f;
    for (int s = 0; s < 4; ++s) acc += scratch[((size_t)(z * 4 + s)) * 4096 + rem];
    acc += (which ? ada2_b : ada1_b)[l * 2048 + n];
    (which ? ss2 : ss1)[(size_t)l * 4096 + rem] = acc;
}

// ---------------------------------------------------------------------------
__global__ __launch_bounds__(256) void in_proj_kernel(const float* __restrict__ x,
                                                      const float* __restrict__ W,
                                                      const float* __restrict__ bias,
                                                      float* __restrict__ h) {
    __shared__ float xs[MEL];
    int row = blockIdx.x;
    int tid = threadIdx.x;
    if (tid < MEL) xs[tid] = x[(size_t)row * MEL + tid];
    __syncthreads();
    for (int c = tid; c < D; c += 256) {
        float acc = bias[c];
        for (int k = 0; k < MEL; ++k) acc += xs[k] * W[(size_t)k * D + c];
        h[(size_t)row * D + c] = acc;
    }
}

// ---------------------------------------------------------------------------
__global__ __launch_bounds__(256) void ln_kernel(const float* __restrict__ x,
                                                 const float* __restrict__ ss,
                                                 void* __restrict__ out,
                                                 int use_mod, int out_bf) {
    int row = blockIdx.x;
    int b = row / T;
    int tid = threadIdx.x;
    float4 v = ((const float4*)(x + (size_t)row * D))[tid];
    float sum = v.x + v.y + v.z + v.w;
    float sq  = v.x * v.x + v.y * v.y + v.z * v.z + v.w * v.w;
    for (int off = 32; off; off >>= 1) {
        sum += __shfl_xor(sum, off);
        sq  += __shfl_xor(sq,  off);
    }
    __shared__ float smem[8];
    int wave = tid >> 6;
    if ((tid & 63) == 0) { smem[wave * 2] = sum; smem[wave * 2 + 1] = sq; }
    __syncthreads();
    sum = smem[0] + smem[2] + smem[4] + smem[6];
    sq  = smem[1] + smem[3] + smem[5] + smem[7];
    float mean = sum * (1.f / D);
    float var  = sq * (1.f / D) - mean * mean;
    float rstd = rsqrtf(var + EPS);
    int c = tid * 4;
    float4 o4;
    if (use_mod) {
        const float* sc = ss + (size_t)b * 2 * D;
        float4 s4  = *(const float4*)(sc + c);
        float4 sh4 = *(const float4*)(sc + D + c);
        o4.x = (v.x - mean) * rstd * (1.f + s4.x) + sh4.x;
        o4.y = (v.y - mean) * rstd * (1.f + s4.y) + sh4.y;
        o4.z = (v.z - mean) * rstd * (1.f + s4.z) + sh4.z;
        o4.w = (v.w - mean) * rstd * (1.f + s4.w) + sh4.w;
    } else {
        o4.x = (v.x - mean) * rstd;
        o4.y = (v.y - mean) * rstd;
        o4.z = (v.z - mean) * rstd;
        o4.w = (v.w - mean) * rstd;
    }
    if (out_bf) {
        __hip_bfloat16* op = (__hip_bfloat16*)out + (size_t)row * D + c;
        op[0] = __float2bfloat16(o4.x);
        op[1] = __float2bfloat16(o4.y);
        op[2] = __float2bfloat16(o4.z);
        op[3] = __float2bfloat16(o4.w);
    } else {
        ((float4*)((float*)out + (size_t)row * D))[tid] = o4;
    }
}

// ---------------------------------------------------------------------------
__global__ __launch_bounds__(256) void transpose_bf16_kernel(const float* __restrict__ W,
                                                             __hip_bfloat16* __restrict__ Wt,
                                                             int K, int N) {
    __shared__ float tile[32][33];
    int nt = blockIdx.x * 32, kt = blockIdx.y * 32;
    int tx = threadIdx.x, ty = threadIdx.y;
#pragma unroll
    for (int i = 0; i < 32; i += 8)
        tile[ty + i][tx] = W[(size_t)(kt + ty + i) * N + nt + tx];
    __syncthreads();
#pragma unroll
    for (int i = 0; i < 32; i += 8)
        Wt[(size_t)(nt + ty + i) * K + kt + tx] = __float2bfloat16(tile[tx][ty + i]);
}

// ---------------------------------------------------------------------------
#define BK 64
#define LDK 72
__global__ __launch_bounds__(256) void gemm_bf16_kernel(const __hip_bfloat16* __restrict__ A,
                                                        const __hip_bfloat16* __restrict__ Bt,
                                                        const float* __restrict__ bias,
                                                        const float* __restrict__ resid,
                                                        void* __restrict__ Cout,
                                                        int M, int N, int K,
                                                        int act, int out_bf) {
    __shared__ short LA[128 * LDK];
    __shared__ short LB[128 * LDK];
    const int tid = threadIdx.x;
    const int wave = tid >> 6, lane = tid & 63;
    const int bm = blockIdx.y * 128, bn = blockIdx.x * 128;
    const int wm = (wave >> 1) * 64, wn = (wave & 1) * 64;
    const int l15 = lane & 15, l4 = lane >> 4;

    f32x4 acc[4][4];
#pragma unroll
    for (int i = 0; i < 4; ++i)
#pragma unroll
        for (int j = 0; j < 4; ++j) acc[i][j] = (f32x4){0.f, 0.f, 0.f, 0.f};

    for (int k0 = 0; k0 < K; k0 += BK) {
        for (int t = wave; t < 18; t += 4) {
            int Gi = t * 64 + lane;
            int row = Gi / 9, g = Gi % 9;
            int gc = (g < 8) ? g * 8 : 0;
            gload16(A + (size_t)(bm + row) * K + k0 + gc, (void*)&LA[t * 512]);
        }
        for (int t = wave; t < 18; t += 4) {
            int Gi = t * 64 + lane;
            int row = Gi / 9, g = Gi % 9;
            int gc = (g < 8) ? g * 8 : 0;
            gload16(Bt + (size_t)(bn + row) * K + k0 + gc, (void*)&LB[t * 512]);
        }
        __syncthreads();
#pragma unroll
        for (int ks = 0; ks < 2; ++ks) {
            const int kb = ks * 32 + l4 * 8;
            bshort8 a[4], b[4];
#pragma unroll
            for (int i = 0; i < 4; ++i)
                a[i] = *(const bshort8*)&LA[(wm + i * 16 + l15) * LDK + kb];
#pragma unroll
            for (int i = 0; i < 4; ++i)
                b[i] = *(const bshort8*)&LB[(wn + i * 16 + l15) * LDK + kb];
#pragma unroll
            for (int i = 0; i < 4; ++i)
#pragma unroll
                for (int j = 0; j < 4; ++j)
                    acc[i][j] = __builtin_amdgcn_mfma_f32_16x16x32_bf16(a[i], b[j], acc[i][j], 0, 0, 0);
        }
        __syncthreads();
    }

#pragma unroll
    for (int im = 0; im < 4; ++im) {
#pragma unroll
        for (int in = 0; in < 4; ++in) {
            int col = bn + wn + in * 16 + l15;
            int row0 = bm + wm + im * 16 + l4 * 4;
            float bi = bias[col];
#pragma unroll
            for (int r = 0; r < 4; ++r) {
                float v = acc[im][in][r] + bi;
                if (act == 1) v = 0.5f * v * (1.f + erff(v * 0.70710678118f));
                size_t idx = (size_t)(row0 + r) * N + col;
                if (resid) v += resid[idx];
                if (out_bf) ((__hip_bfloat16*)Cout)[idx] = __float2bfloat16(v);
                else        ((float*)Cout)[idx] = v;
            }
        }
    }
}

// ---------------------------------------------------------------------------
__global__ void rope_tables_kernel(float* __restrict__ cs) {
    int id = blockIdx.x * blockDim.x + threadIdx.x;
    if (id >= T * 32) return;
    int t = id >> 5, i = id & 31;
    double freq = 1.0 / pow(10000.0, (double)(2 * i) / (double)DH);
    double ang = (double)t * freq;
    cs[t * 64 + i]      = (float)cos(ang);
    cs[t * 64 + 32 + i] = (float)sin(ang);
}

// ---------------------------------------------------------------------------
// qkv bf16 [B,T,3,H,DH] -> Qb [BH,T,DH] (rope), Kb [BH,WIN,DH] (rope), Vtb [BH,DH,WIN]
__global__ void repack_kernel(const __hip_bfloat16* __restrict__ qkv,
                              const float* __restrict__ cs,
                              __hip_bfloat16* __restrict__ Qb,
                              __hip_bfloat16* __restrict__ Kb,
                              __hip_bfloat16* __restrict__ Vtb) {
    int id = blockIdx.x * blockDim.x + threadIdx.x;   // B*T*H*32
    if (id >= B * T * H * 32) return;
    int i  = id & 31;
    int h  = (id >> 5) & 15;
    int t  = (id >> 9) & 2047;
    int b  = id >> 20;
    int bh = b * H + h;
    float c = cs[t * 64 + i];
    float s = cs[t * 64 + 32 + i];
    size_t base = ((size_t)(b * T + t) * 3) * D + h * DH + 2 * i;
    float q0 = bf2f(qkv[base]), q1 = bf2f(qkv[base + 1]);
    size_t qo = ((size_t)bh * T + t) * DH + 2 * i;
    Qb[qo]     = __float2bfloat16(q0 * c - q1 * s);
    Qb[qo + 1] = __float2bfloat16(q0 * s + q1 * c);
    if (t >= T - WIN) {
        int j = t - (T - WIN);
        float k0 = bf2f(qkv[base + D]), k1 = bf2f(qkv[base + D + 1]);
        size_t ko = ((size_t)bh * WIN + j) * DH + 2 * i;
        Kb[ko]     = __float2bfloat16(k0 * c - k1 * s);
        Kb[ko + 1] = __float2bfloat16(k0 * s + k1 * c);
        Vtb[((size_t)bh * DH + 2 * i) * WIN + j]     = qkv[base + 2 * D];
        Vtb[((size_t)bh * DH + 2 * i + 1) * WIN + j] = qkv[base + 2 * D + 1];
    }
}

// ---------------------------------------------------------------------------
// MFMA flash attention over the fixed last-WIN-keys window with causal mask j<=q.
#define AT_LDSK 72
#define AT_LDSV 136
__global__ __launch_bounds__(256) void attn_mfma_kernel(const __hip_bfloat16* __restrict__ Qb,
                                                        const __hip_bfloat16* __restrict__ Kb,
                                                        const __hip_bfloat16* __restrict__ Vtb,
                                                        __hip_bfloat16* __restrict__ o) {
    __shared__ short Ks[128 * AT_LDSK];     // 18432 B
    __shared__ short Vts[64 * AT_LDSV];     // 17408 B
    __shared__ short Ps[4][16 * AT_LDSV];   // 17408 B
    const int tid = threadIdx.x;
    const int wq = tid >> 6, lane = tid & 63;
    const int l15 = lane & 15, l4 = lane >> 4;
    const int qt = blockIdx.x & 31, bh = blockIdx.x >> 5;
    const int q0 = qt * 64;

    const int qrow = q0 + wq * 16 + l15;
    bshort8 qf0 = *(const bshort8*)(Qb + ((size_t)bh * T + qrow) * DH + l4 * 8);
    bshort8 qf1 = *(const bshort8*)(Qb + ((size_t)bh * T + qrow) * DH + 32 + l4 * 8);

    f32x4 oacc[4];
#pragma unroll
    for (int nt = 0; nt < 4; ++nt) oacc[nt] = (f32x4){0.f, 0.f, 0.f, 0.f};
    float m_r[4], l_r[4];
#pragma unroll
    for (int r = 0; r < 4; ++r) { m_r[r] = -INFINITY; l_r[r] = 0.f; }

    const bool need_mask = (q0 < WIN);
    const int nch = need_mask ? ((q0 + 63) / 128 + 1) : 4;

    for (int kc = 0; kc < nch; ++kc) {
        __syncthreads();
        for (int t = wq; t < 18; t += 4) {        // K chunk [128,64] -> padded 72
            int Gi = t * 64 + lane;
            int row = Gi / 9, g = Gi % 9;
            int g8 = (g < 8) ? g : 0;
            gload16(Kb + ((size_t)bh * WIN + kc * 128 + row) * DH + g8 * 8,
                    (void*)&Ks[t * 512]);
        }
        for (int t = wq; t < 17; t += 4) {        // V^T chunk [64,128] -> padded 136
            int Gi = t * 64 + lane;
            int row = Gi / 17, g = Gi % 17;
            int g16 = (g < 16) ? g : 0;
            gload16(Vtb + ((size_t)bh * DH + row) * WIN + kc * 128 + g16 * 8,
                    (void*)&Vts[t * 512]);
        }
        __syncthreads();

        // S[16,128] = Q K^T
        f32x4 s[8];
#pragma unroll
        for (int in = 0; in < 8; ++in) {
            bshort8 kf0 = *(const bshort8*)&Ks[(in * 16 + l15) * AT_LDSK + l4 * 8];
            bshort8 kf1 = *(const bshort8*)&Ks[(in * 16 + l15) * AT_LDSK + 32 + l4 * 8];
            f32x4 z = (f32x4){0.f, 0.f, 0.f, 0.f};
            z = __builtin_amdgcn_mfma_f32_16x16x32_bf16(qf0, kf0, z, 0, 0, 0);
            z = __builtin_amdgcn_mfma_f32_16x16x32_bf16(qf1, kf1, z, 0, 0, 0);
            s[in] = z;
        }

        // online softmax per row (row = l4*4+r within wave's 16-row tile)
#pragma unroll
        for (int r = 0; r < 4; ++r) {
            int qg = q0 + wq * 16 + l4 * 4 + r;
            float mx = -INFINITY;
#pragma unroll
            for (int in = 0; in < 8; ++in) {
                float v = s[in][r] * 0.125f;
                if (need_mask) {
                    int key = kc * 128 + in * 16 + l15;
                    if (key > qg) v = -INFINITY;
                }
                s[in][r] = v;
                mx = fmaxf(mx, v);
            }
            for (int off = 8; off; off >>= 1) mx = fmaxf(mx, __shfl_xor(mx, off));
            mx = fmaxf(mx, m_r[r]);
            float alpha = expf(m_r[r] - mx);      // 0 on first chunk
            m_r[r] = mx;
            float sum = 0.f;
#pragma unroll
            for (int in = 0; in < 8; ++in) {
                float p = expf(s[in][r] - mx);    // masked (-inf) -> 0
                s[in][r] = p;
                sum += p;
            }
            for (int off = 8; off; off >>= 1) sum += __shfl_xor(sum, off);
            l_r[r] = l_r[r] * alpha + sum;
#pragma unroll
            for (int nt = 0; nt < 4; ++nt) {
                oacc[nt][r] *= alpha;
            }
#pragma unroll
            for (int in = 0; in < 8; ++in) {
                __hip_bfloat16 pb = __float2bfloat16(s[in][r]);
                Ps[wq][(l4 * 4 + r) * AT_LDSV + in * 16 + l15] = *(short*)&pb;
            }
        }

        // O += P V  (A-frag from Ps, B-frag from Vts)
#pragma unroll
        for (int kt = 0; kt < 4; ++kt) {
            bshort8 pa = *(const bshort8*)&Ps[wq][l15 * AT_LDSV + kt * 32 + l4 * 8];
#pragma unroll
            for (int nt = 0; nt < 4; ++nt) {
                bshort8 vb = *(const bshort8*)&Vts[(nt * 16 + l15) * AT_LDSV + kt * 32 + l4 * 8];
                oacc[nt] = __builtin_amdgcn_mfma_f32_16x16x32_bf16(pa, vb, oacc[nt], 0, 0, 0);
            }
        }
    }

    const int bb = bh >> 4, hh = bh & 15;
#pragma unroll
    for (int nt = 0; nt < 4; ++nt) {
#pragma unroll
        for (int r = 0; r < 4; ++r) {
            int qg = q0 + wq * 16 + l4 * 4 + r;
            int dim = nt * 16 + l15;
            float v = oacc[nt][r] / l_r[r];
            o[((size_t)(bb * T + qg)) * D + hh * DH + dim] = __float2bfloat16(v);
        }
    }
}

// ---------------------------------------------------------------------------
__global__ __launch_bounds__(128) void out_proj_kernel(const float* __restrict__ hn,
                                                       const float* __restrict__ W,
                                                       const float* __restrict__ bias,
                                                       float* __restrict__ out) {
    __shared__ float hs[D];
    int row = blockIdx.x;
    int tid = threadIdx.x;
    for (int c = tid; c < D; c += 128) hs[c] = hn[(size_t)row * D + c];
    __syncthreads();
    if (tid < MEL) {
        float acc = bias[tid];
        for (int k = 0; k < D; ++k) acc += hs[k] * W[(size_t)k * MEL + tid];
        out[(size_t)row * MEL + tid] = acc;
    }
}

// ---------------------------------------------------------------------------
extern "C" void kernel_launch(void* const* d_in, const int* in_sizes, int n_in,
                              void* d_out, int out_size, void* d_ws, size_t ws_size,
                              hipStream_t stream) {
    const float* x      = (const float*)d_in[0];
    const float* t      = (const float*)d_in[1];
    const float* W_in   = (const float*)d_in[2];
    const float* b_in   = (const float*)d_in[3];
    const float* Wt1    = (const float*)d_in[4];
    const float* bt1    = (const float*)d_in[5];
    const float* Wt2    = (const float*)d_in[6];
    const float* bt2    = (const float*)d_in[7];
    const float* Wcm    = (const float*)d_in[8];
    const float* bcm    = (const float*)d_in[9];
    const float* ada1_W = (const float*)d_in[10];
    const float* ada1_b = (const float*)d_in[11];
    const float* qkv_W  = (const float*)d_in[12];
    const float* qkv_b  = (const float*)d_in[13];
    const float* attno_W= (const float*)d_in[14];
    const float* attno_b= (const float*)d_in[15];
    const float* ada2_W = (const float*)d_in[16];
    const float* ada2_b = (const float*)d_in[17];
    const float* mlp_W1 = (const float*)d_in[18];
    const float* mlp_b1 = (const float*)d_in[19];
    const float* mlp_W2 = (const float*)d_in[20];
    const float* mlp_b2 = (const float*)d_in[21];
    const float* W_out  = (const float*)d_in[22];
    const float* b_out  = (const float*)d_in[23];
    float* out = (float*)d_out;

    float* ws = (float*)d_ws;
    float* h      = ws;                                        //  4,194,304
    float* bigA   = ws + 4194304;                              //  8,388,608 (qkvbf | ffbf | final hn)
    __hip_bfloat16* qkvbf = (__hip_bfloat16*)bigA;
    __hip_bfloat16* ffbf  = (__hip_bfloat16*)bigA;
    __hip_bfloat16* hnbf  = (__hip_bfloat16*)(ws + 12582912);  //  2,097,152 (also obf)
    __hip_bfloat16* obf   = hnbf;
    __hip_bfloat16* wtb   = (__hip_bfloat16*)(ws + 14680064);  //  6,291,456 floats worth
    __hip_bfloat16* wt_qkv = wtb;
    __hip_bfloat16* wt_at  = wtb + 3145728;
    __hip_bfloat16* wt_m1  = wtb + 4194304;
    __hip_bfloat16* wt_m2  = wtb + 8388608;
    float* ropecs = ws + 20971520;                             //    131,072
    __hip_bfloat16* Qb  = (__hip_bfloat16*)(ws + 21102592);    //  2,097,152
    __hip_bfloat16* Kb  = (__hip_bfloat16*)(ws + 23199744);    //    524,288
    __hip_bfloat16* Vtb = (__hip_bfloat16*)(ws + 23724032);    //    524,288
    float* temb0 = ws + 24248320;
    float* tembh = temb0 + B * CD;
    float* temb2 = tembh + B * CD;
    float* cond  = temb2 + B * CD;
    float* ss1   = cond + B * D;                               // L*B*2D = 24576
    float* ss2   = ss1 + L * B * 2 * D;
    float* gemv_scratch = ss2 + L * B * 2 * D;                 // 8*2048
    float* ada_scratch  = gemv_scratch + 8 * 2048;             // 48*4096

    const int M = B * T;   // 4096

    rope_tables_kernel<<<(T * 32 + 255) / 256, 256, 0, stream>>>(ropecs);

    // time-embedding chain (split-K GEMVs)
    temb0_kernel<<<(B * CD + 255) / 256, 256, 0, stream>>>(t, temb0);
    gemv_part_kernel<<<dim3(8, 8), 256, 0, stream>>>(temb0, Wt1, gemv_scratch, CD, CD, 128);
    gemv_reduce_kernel<<<8, 256, 0, stream>>>(gemv_scratch, bt1, tembh, 2048, CD, 8, 1);
    gemv_part_kernel<<<dim3(8, 8), 256, 0, stream>>>(tembh, Wt2, gemv_scratch, CD, CD, 128);
    gemv_reduce_kernel<<<8, 256, 0, stream>>>(gemv_scratch, bt2, temb2, 2048, CD, 8, 0);
    gemv_part_kernel<<<dim3(8, 8), 256, 0, stream>>>(temb2, Wcm, gemv_scratch, CD, D, 128);
    gemv_reduce_kernel<<<8, 256, 0, stream>>>(gemv_scratch, bcm, cond, 2048, D, 8, 1);
    // all 12 ada GEMVs batched (stride 4096 = B*2D)
    ada_part_kernel<<<dim3(16, 4, 12), 256, 0, stream>>>(cond, ada1_W, ada2_W, ada_scratch);
    ada_reduce_kernel<<<(12 * 4096) / 256, 256, 0, stream>>>(ada_scratch, ada1_b, ada2_b, ss1, ss2);

    in_proj_kernel<<<M, 256, 0, stream>>>(x, W_in, b_in, h);

    for (int l = 0; l < L; ++l) {
        transpose_bf16_kernel<<<dim3(3 * D / 32, D / 32), dim3(32, 8), 0, stream>>>(
            qkv_W + (size_t)l * D * 3 * D, wt_qkv, D, 3 * D);
        transpose_bf16_kernel<<<dim3(D / 32, D / 32), dim3(32, 8), 0, stream>>>(
            attno_W + (size_t)l * D * D, wt_at, D, D);
        transpose_bf16_kernel<<<dim3(FF / 32, D / 32), dim3(32, 8), 0, stream>>>(
            mlp_W1 + (size_t)l * D * FF, wt_m1, D, FF);
        transpose_bf16_kernel<<<dim3(D / 32, FF / 32), dim3(32, 8), 0, stream>>>(
            mlp_W2 + (size_t)l * FF * D, wt_m2, FF, D);

        ln_kernel<<<M, 256, 0, stream>>>(h, ss1 + (size_t)l * B * 2 * D, hnbf, 1, 1);
        gemm_bf16_kernel<<<dim3(3 * D / 128, M / 128), 256, 0, stream>>>(
            hnbf, wt_qkv, qkv_b + (size_t)l * 3 * D, nullptr, qkvbf,
            M, 3 * D, D, 0, 1);
        repack_kernel<<<(B * T * H * 32 + 255) / 256, 256, 0, stream>>>(
            qkvbf, ropecs, Qb, Kb, Vtb);
        attn_mfma_kernel<<<B * H * (T / 64), 256, 0, stream>>>(Qb, Kb, Vtb, obf);
        gemm_bf16_kernel<<<dim3(D / 128, M / 128), 256, 0, stream>>>(
            obf, wt_at, attno_b + (size_t)l * D, h, h, M, D, D, 0, 0);
        ln_kernel<<<M, 256, 0, stream>>>(h, ss2 + (size_t)l * B * 2 * D, hnbf, 1, 1);
        gemm_bf16_kernel<<<dim3(FF / 128, M / 128), 256, 0, stream>>>(
            hnbf, wt_m1, mlp_b1 + (size_t)l * FF, nullptr, ffbf,
            M, FF, D, 1, 1);
        gemm_bf16_kernel<<<dim3(D / 128, M / 128), 256, 0, stream>>>(
            ffbf, wt_m2, mlp_b2 + (size_t)l * D, h, h, M, D, FF, 0, 0);
    }

    ln_kernel<<<M, 256, 0, stream>>>(h, nullptr, bigA, 0, 0);
    out_proj_kernel<<<M, 128, 0, stream>>>(bigA, W_out, b_out, out);
}